// Round 1
// baseline (157.240 us; speedup 1.0000x reference)
//
#include <hip/hip_runtime.h>
#include <hip/hip_fp16.h>

// Problem constants (match reference)
#define BB 8
#define NN 1024
#define IN_DIM 512
#define HH 8
#define SUP 64
#define HS (HH * SUP)   // 512

typedef _Float16 half8 __attribute__((ext_vector_type(8)));
typedef float floatx4 __attribute__((ext_vector_type(4)));

// ---------------------------------------------------------------------------
// k0: W[h][i][o] fp32  ->  Wt[h][o][i] fp16   (transpose + downconvert)
// grid (IN_DIM/64, H), block 256
// ---------------------------------------------------------------------------
__global__ __launch_bounds__(256) void k0_transpose_w(const float* __restrict__ W,
                                                      _Float16* __restrict__ Wt) {
    __shared__ float tile[64][65];
    const int it = blockIdx.x;       // i-tile
    const int h  = blockIdx.y;
    const int t  = threadIdx.x;

    {
        const int i  = t >> 2;             // 0..63
        const int o0 = (t & 3) * 16;       // 16 floats per thread
        const float* src = W + ((size_t)h * IN_DIM + it * 64 + i) * SUP + o0;
#pragma unroll
        for (int j = 0; j < 4; j++) {
            float4 v = ((const float4*)src)[j];
            tile[i][o0 + j * 4 + 0] = v.x;
            tile[i][o0 + j * 4 + 1] = v.y;
            tile[i][o0 + j * 4 + 2] = v.z;
            tile[i][o0 + j * 4 + 3] = v.w;
        }
    }
    __syncthreads();
    {
        const int o  = t >> 2;
        const int i0 = (t & 3) * 16;
        _Float16 buf[16];
#pragma unroll
        for (int j = 0; j < 16; j++) buf[j] = (_Float16)tile[i0 + j][o];
        _Float16* dst = Wt + ((size_t)h * SUP + o) * IN_DIM + it * 64 + i0;
        *(half8*)dst       = *(half8*)buf;
        *(half8*)(dst + 8) = *(half8*)(buf + 8);
    }
}

// ---------------------------------------------------------------------------
// k1: projection. Per (b,h): C[1024,64] = X_b[1024,512] @ W_h[512,64]
// MFMA f16 (fp32 accum). Output stored TRANSPOSED: Pt[bh][o][n] fp16.
// grid (N/64, B*H), block 256 (4 waves); tile 64n x 64o, K-step 32.
// ---------------------------------------------------------------------------
__global__ __launch_bounds__(256) void k1_proj(const float* __restrict__ X,
                                               const _Float16* __restrict__ Wt,
                                               _Float16* __restrict__ Pt) {
    __shared__ __align__(16) _Float16 xs[64 * 40];   // [n][k], stride 40 halves
    __shared__ __align__(16) _Float16 wsh[64 * 40];  // [o][k]
    __shared__ __align__(16) _Float16 po[64 * 72];   // epilogue [o][n]

    const int bh = blockIdx.y;
    const int b  = bh >> 3;
    const int h  = bh & 7;
    const int n0 = blockIdx.x * 64;
    const int t    = threadIdx.x;
    const int wave = t >> 6;
    const int lane = t & 63;
    const int quad = lane >> 4;
    const int l15  = lane & 15;
    const int row  = t >> 2;         // staging row 0..63
    const int koff = (t & 3) * 8;    // staging k offset

    floatx4 acc[4];
#pragma unroll
    for (int i = 0; i < 4; i++) acc[i] = {0.f, 0.f, 0.f, 0.f};

    const float*    xbase = X + ((size_t)b * NN + n0 + row) * IN_DIM;
    const _Float16* wbase = Wt + ((size_t)h * SUP + row) * IN_DIM;

    for (int k0 = 0; k0 < IN_DIM; k0 += 32) {
        // stage X tile (fp32 -> fp16)
        {
            const float* src = xbase + k0 + koff;
            float4 xa = ((const float4*)src)[0];
            float4 xb = ((const float4*)src)[1];
            _Float16 xh[8] = {(_Float16)xa.x, (_Float16)xa.y, (_Float16)xa.z, (_Float16)xa.w,
                              (_Float16)xb.x, (_Float16)xb.y, (_Float16)xb.z, (_Float16)xb.w};
            *(half8*)&xs[row * 40 + koff] = *(half8*)xh;
        }
        // stage Wt tile (already fp16, contiguous in k)
        {
            *(half8*)&wsh[row * 40 + koff] = *(const half8*)(wbase + k0 + koff);
        }
        __syncthreads();
        half8 af = *(const half8*)&xs[(wave * 16 + l15) * 40 + quad * 8];
#pragma unroll
        for (int ct = 0; ct < 4; ct++) {
            half8 bf = *(const half8*)&wsh[(ct * 16 + l15) * 40 + quad * 8];
            acc[ct] = __builtin_amdgcn_mfma_f32_16x16x32_f16(af, bf, acc[ct], 0, 0, 0);
        }
        __syncthreads();
    }

    // epilogue: C[m=n][n=o] -> po[o][n] fp16, then coalesced store to Pt[bh][o][n]
#pragma unroll
    for (int ct = 0; ct < 4; ct++) {
#pragma unroll
        for (int r = 0; r < 4; r++) {
            int o = ct * 16 + l15;
            int n = wave * 16 + quad * 4 + r;
            po[o * 72 + n] = (_Float16)acc[ct][r];
        }
    }
    __syncthreads();
    {
        const int o   = t >> 2;
        const int nof = (t & 3) * 16;
        _Float16* dst = Pt + ((size_t)bh * SUP + o) * NN + n0 + nof;
        *(half8*)dst       = *(const half8*)&po[o * 72 + nof];
        *(half8*)(dst + 8) = *(const half8*)&po[o * 72 + nof + 8];
    }
}

// ---------------------------------------------------------------------------
// k1s: s = P.w1 + b1, t = P.w2 + b2 per (b,h,n); partial tmax per quarter.
// grid (4, B*H), block 256 (one n per thread).
// ---------------------------------------------------------------------------
__global__ __launch_bounds__(256) void k1s_st(const _Float16* __restrict__ Pt,
                                              const float* __restrict__ w1,
                                              const float* __restrict__ b1,
                                              const float* __restrict__ w2,
                                              const float* __restrict__ b2,
                                              float* __restrict__ s_g,
                                              float* __restrict__ t_g,
                                              float* __restrict__ tmax4) {
    const int q  = blockIdx.x;
    const int bh = blockIdx.y;
    const int h  = bh & 7;
    const int t  = threadIdx.x;
    const int n  = q * 256 + t;

    __shared__ float w1s[64], w2s[64];
    __shared__ float red[256];
    if (t < 64) w1s[t] = w1[h * 64 + t];
    else if (t < 128) w2s[t - 64] = w2[h * 64 + (t - 64)];
    __syncthreads();

    const _Float16* base = Pt + (size_t)bh * SUP * NN + n;
    float sa = 0.f, ta = 0.f;
#pragma unroll
    for (int o = 0; o < 64; o++) {
        float p = (float)base[(size_t)o * NN];
        sa += p * w1s[o];
        ta += p * w2s[o];
    }
    sa += b1[h];
    ta += b2[h];
    s_g[(size_t)bh * NN + n] = sa;
    t_g[(size_t)bh * NN + n] = ta;

    red[t] = ta;
    __syncthreads();
    for (int off = 128; off > 0; off >>= 1) {
        if (t < off) red[t] = fmaxf(red[t], red[t + off]);
        __syncthreads();
    }
    if (t == 0) tmax4[bh * 4 + q] = red[0];
}

// ---------------------------------------------------------------------------
// k2: fused masked-softmax attention + aggregation.
// Per block: one (b,h), 64 query rows. Flash-style over 32-key tiles.
// grid (N/64, B*H), block 256 (4 waves).
// ---------------------------------------------------------------------------
__global__ __launch_bounds__(256) void k2_attn(const float* __restrict__ A,
                                               const _Float16* __restrict__ Pt,
                                               const float* __restrict__ s_g,
                                               const float* __restrict__ t_g,
                                               const float* __restrict__ tmax4,
                                               float* __restrict__ out) {
    __shared__ __align__(16) _Float16 vts[64 * 40];  // V^T tile  [o][m]
    __shared__ __align__(16) _Float16 als[64 * 40];  // alpha tile [n][m]
    __shared__ __align__(16) float tl[NN];           // t[b,h,:]
    __shared__ float sl[64], cl[64];
    __shared__ float zred[256];
    __shared__ float zinv[64];

    const int bh = blockIdx.y;
    const int b  = bh >> 3;
    const int h  = bh & 7;
    const int n0 = blockIdx.x * 64;
    const int t    = threadIdx.x;
    const int wave = t >> 6;
    const int lane = t & 63;
    const int quad = lane >> 4;
    const int l15  = lane & 15;
    const int row  = t >> 2;       // 0..63
    const int mg   = t & 3;        // m-group (8 m's each)

    const float tmax = fmaxf(fmaxf(tmax4[bh * 4 + 0], tmax4[bh * 4 + 1]),
                             fmaxf(tmax4[bh * 4 + 2], tmax4[bh * 4 + 3]));

    // stage t[b,h,:] (1024 floats)
    ((float4*)tl)[t] = ((const float4*)(t_g + (size_t)bh * NN))[t];
    if (t < 64) {
        float sv = s_g[(size_t)bh * NN + n0 + t];
        sl[t] = sv;
        float x = sv + tmax;
        cl[t] = x > 0.f ? x : 0.01f * x;   // c_n = lrelu(s_n + tmax) >= row max logit
    }
    __syncthreads();

    floatx4 acc[4];
#pragma unroll
    for (int i = 0; i < 4; i++) acc[i] = {0.f, 0.f, 0.f, 0.f};
    float zp = 0.f;

    const float*    abase = A + ((size_t)b * NN + n0 + row) * NN + mg * 8;
    const _Float16* pbase = Pt + ((size_t)bh * SUP + row) * NN + mg * 8;

    for (int m0 = 0; m0 < NN; m0 += 32) {
        // stage V^T tile (fp16, contiguous in m)
        *(half8*)&vts[row * 40 + mg * 8] = *(const half8*)(pbase + m0);

        // compute alpha tile: w = A * exp(lrelu(s+t) - c)
        {
            const float* ap = abase + m0;
            float4 a0 = ((const float4*)ap)[0];
            float4 a1 = ((const float4*)ap)[1];
            float av[8] = {a0.x, a0.y, a0.z, a0.w, a1.x, a1.y, a1.z, a1.w};
            const float sv = sl[row];
            const float c  = cl[row];
            _Float16 wbuf[8];
#pragma unroll
            for (int j = 0; j < 8; j++) {
                float x = sv + tl[m0 + mg * 8 + j];
                float l = x > 0.f ? x : 0.01f * x;
                float e = __expf(l - c);
                float w = av[j] * e;     // A is exactly 0.0 or 1.0
                zp += w;
                wbuf[j] = (_Float16)w;
            }
            *(half8*)&als[row * 40 + mg * 8] = *(half8*)wbuf;
        }
        __syncthreads();

        half8 af = *(const half8*)&als[(wave * 16 + l15) * 40 + quad * 8];
#pragma unroll
        for (int ct = 0; ct < 4; ct++) {
            half8 bf = *(const half8*)&vts[(ct * 16 + l15) * 40 + quad * 8];
            acc[ct] = __builtin_amdgcn_mfma_f32_16x16x32_f16(af, bf, acc[ct], 0, 0, 0);
        }
        __syncthreads();
    }

    // reduce Z per row (4 partials per row)
    zred[t] = zp;
    __syncthreads();
    if (t < 64) {
        float z = zred[t * 4] + zred[t * 4 + 1] + zred[t * 4 + 2] + zred[t * 4 + 3];
        zinv[t] = 1.0f / z;
    }
    __syncthreads();

    // epilogue: out[b][n][h*64+o] = relu(acc / Z)
#pragma unroll
    for (int r = 0; r < 4; r++) {
        const int rr = wave * 16 + quad * 4 + r;
        const float rz = zinv[rr];
#pragma unroll
        for (int ct = 0; ct < 4; ct++) {
            float v = acc[ct][r] * rz;
            v = v > 0.f ? v : 0.f;
            out[((size_t)b * NN + n0 + rr) * HS + h * SUP + ct * 16 + l15] = v;
        }
    }
}

// ---------------------------------------------------------------------------
extern "C" void kernel_launch(void* const* d_in, const int* in_sizes, int n_in,
                              void* d_out, int out_size, void* d_ws, size_t ws_size,
                              hipStream_t stream) {
    const float* A  = (const float*)d_in[0];
    const float* X  = (const float*)d_in[1];
    const float* W  = (const float*)d_in[2];
    const float* w1 = (const float*)d_in[3];
    const float* b1 = (const float*)d_in[4];
    const float* w2 = (const float*)d_in[5];
    const float* b2 = (const float*)d_in[6];
    float* out = (float*)d_out;

    char* ws = (char*)d_ws;
    _Float16* Wt    = (_Float16*)(ws);                       // 8*64*512*2   = 524288
    _Float16* Pt    = (_Float16*)(ws + 524288);              // 64*64*1024*2 = 8388608
    float*    s_g   = (float*)(ws + 524288 + 8388608);       // 65536*4      = 262144
    float*    t_g   = (float*)(ws + 524288 + 8388608 + 262144);
    float*    tmax4 = (float*)(ws + 524288 + 8388608 + 2 * 262144);  // 256 floats

    hipLaunchKernelGGL(k0_transpose_w, dim3(IN_DIM / 64, HH), dim3(256), 0, stream, W, Wt);
    hipLaunchKernelGGL(k1_proj, dim3(NN / 64, BB * HH), dim3(256), 0, stream, X, Wt, Pt);
    hipLaunchKernelGGL(k1s_st, dim3(4, BB * HH), dim3(256), 0, stream,
                       Pt, w1, b1, w2, b2, s_g, t_g, tmax4);
    hipLaunchKernelGGL(k2_attn, dim3(NN / 64, BB * HH), dim3(256), 0, stream,
                       A, Pt, s_g, t_g, tmax4, out);
}

// Round 2
// 140.603 us; speedup vs baseline: 1.1183x; 1.1183x over previous
//
#include <hip/hip_runtime.h>
#include <hip/hip_fp16.h>

// Problem constants (match reference)
#define BB 8
#define NN 1024
#define IN_DIM 512
#define HH 8
#define SUP 64
#define HS (HH * SUP)   // 512

typedef _Float16 half8 __attribute__((ext_vector_type(8)));
typedef float floatx4 __attribute__((ext_vector_type(4)));

// ---------------------------------------------------------------------------
// k0: W[h][i][o] fp32  ->  Wt[h][o][i] fp16   (transpose + downconvert)
// grid (IN_DIM/64, H), block 256
// ---------------------------------------------------------------------------
__global__ __launch_bounds__(256) void k0_transpose_w(const float* __restrict__ W,
                                                      _Float16* __restrict__ Wt) {
    __shared__ float tile[64][65];
    const int it = blockIdx.x;
    const int h  = blockIdx.y;
    const int t  = threadIdx.x;
    {
        const int i  = t >> 2;
        const int o0 = (t & 3) * 16;
        const float* src = W + ((size_t)h * IN_DIM + it * 64 + i) * SUP + o0;
#pragma unroll
        for (int j = 0; j < 4; j++) {
            float4 v = ((const float4*)src)[j];
            tile[i][o0 + j * 4 + 0] = v.x;
            tile[i][o0 + j * 4 + 1] = v.y;
            tile[i][o0 + j * 4 + 2] = v.z;
            tile[i][o0 + j * 4 + 3] = v.w;
        }
    }
    __syncthreads();
    {
        const int o  = t >> 2;
        const int i0 = (t & 3) * 16;
        _Float16 buf[16];
#pragma unroll
        for (int j = 0; j < 16; j++) buf[j] = (_Float16)tile[i0 + j][o];
        _Float16* dst = Wt + ((size_t)h * SUP + o) * IN_DIM + it * 64 + i0;
        *(half8*)dst       = *(half8*)buf;
        *(half8*)(dst + 8) = *(half8*)(buf + 8);
    }
}

// ---------------------------------------------------------------------------
// kpack: A[b][n][m] fp32 (0/1) -> bitmask Am[b*N+n][128 bytes].
// One wave per row; ballot packs 64 keys per iteration. grid 2048, block 256.
// ---------------------------------------------------------------------------
__global__ __launch_bounds__(256) void kpack(const float* __restrict__ A,
                                             unsigned char* __restrict__ Am) {
    const int gw   = blockIdx.x * 4 + (threadIdx.x >> 6);  // row = b*N+n, 0..8191
    const int lane = threadIdx.x & 63;
    const float* arow = A + (size_t)gw * NN;
    unsigned long long keep = 0;
#pragma unroll
    for (int g = 0; g < 16; g++) {
        float a = arow[g * 64 + lane];
        unsigned long long bal = __ballot(a > 0.5f);
        if (lane == g) keep = bal;
    }
    if (lane < 16)
        *(unsigned long long*)(Am + (size_t)gw * 128 + lane * 8) = keep;
}

// ---------------------------------------------------------------------------
// k1: projection + attention logits. Per (b,h): P[1024,64] = X_b @ W_h.
// Stores Pt[bh][o][n] fp16; computes s = P.w1+b1, t = P.w2+b2 from the fp32
// accumulators (shuffle-reduce), and per-tile tmax partials.
// grid (N/64, B*H), block 256 (4 waves).
// ---------------------------------------------------------------------------
__global__ __launch_bounds__(256) void k1_proj(const float* __restrict__ X,
                                               const _Float16* __restrict__ Wt,
                                               const float* __restrict__ w1,
                                               const float* __restrict__ b1,
                                               const float* __restrict__ w2,
                                               const float* __restrict__ b2,
                                               _Float16* __restrict__ Pt,
                                               float* __restrict__ s_g,
                                               float* __restrict__ t_g,
                                               float* __restrict__ tmax16) {
    __shared__ __align__(16) _Float16 xs[64 * 40];
    __shared__ __align__(16) _Float16 wsh[64 * 40];
    __shared__ __align__(16) _Float16 po[64 * 72];
    __shared__ float tred[64];

    const int bh = blockIdx.y;
    const int b  = bh >> 3;
    const int h  = bh & 7;
    const int n0 = blockIdx.x * 64;
    const int t    = threadIdx.x;
    const int wave = t >> 6;
    const int lane = t & 63;
    const int quad = lane >> 4;
    const int l15  = lane & 15;
    const int row  = t >> 2;
    const int koff = (t & 3) * 8;

    floatx4 acc[4];
#pragma unroll
    for (int i = 0; i < 4; i++) acc[i] = {0.f, 0.f, 0.f, 0.f};

    // per-lane w1/w2 values for the s/t epilogue
    float w1v[4], w2v[4];
#pragma unroll
    for (int ct = 0; ct < 4; ct++) {
        w1v[ct] = w1[h * 64 + ct * 16 + l15];
        w2v[ct] = w2[h * 64 + ct * 16 + l15];
    }
    const float b1h = b1[h];
    const float b2h = b2[h];

    const float*    xbase = X + ((size_t)b * NN + n0 + row) * IN_DIM;
    const _Float16* wbase = Wt + ((size_t)h * SUP + row) * IN_DIM;

    // prefetch k=0
    float4 xa = ((const float4*)(xbase + koff))[0];
    float4 xb = ((const float4*)(xbase + koff))[1];
    half8  wv = *(const half8*)(wbase + koff);

    for (int k0 = 0; k0 < IN_DIM; k0 += 32) {
        {
            _Float16 xh[8] = {(_Float16)xa.x, (_Float16)xa.y, (_Float16)xa.z, (_Float16)xa.w,
                              (_Float16)xb.x, (_Float16)xb.y, (_Float16)xb.z, (_Float16)xb.w};
            *(half8*)&xs[row * 40 + koff] = *(half8*)xh;
            *(half8*)&wsh[row * 40 + koff] = wv;
        }
        __syncthreads();
        if (k0 + 32 < IN_DIM) {
            const float* src = xbase + k0 + 32 + koff;
            xa = ((const float4*)src)[0];
            xb = ((const float4*)src)[1];
            wv = *(const half8*)(wbase + k0 + 32 + koff);
        }
        half8 af = *(const half8*)&xs[(wave * 16 + l15) * 40 + quad * 8];
#pragma unroll
        for (int ct = 0; ct < 4; ct++) {
            half8 bf = *(const half8*)&wsh[(ct * 16 + l15) * 40 + quad * 8];
            acc[ct] = __builtin_amdgcn_mfma_f32_16x16x32_f16(af, bf, acc[ct], 0, 0, 0);
        }
        __syncthreads();
    }

    // epilogue 1: po[o][n] fp16 tile + s/t from fp32 accumulators
#pragma unroll
    for (int ct = 0; ct < 4; ct++) {
#pragma unroll
        for (int r = 0; r < 4; r++) {
            int o = ct * 16 + l15;
            int n = wave * 16 + quad * 4 + r;
            po[o * 72 + n] = (_Float16)acc[ct][r];
        }
    }
#pragma unroll
    for (int r = 0; r < 4; r++) {
        float sp = 0.f, tp = 0.f;
#pragma unroll
        for (int ct = 0; ct < 4; ct++) {
            sp += acc[ct][r] * w1v[ct];
            tp += acc[ct][r] * w2v[ct];
        }
#pragma unroll
        for (int off = 1; off < 16; off <<= 1) {
            sp += __shfl_xor(sp, off);
            tp += __shfl_xor(tp, off);
        }
        if (l15 == 0) {
            const int n = wave * 16 + quad * 4 + r;
            s_g[(size_t)bh * NN + n0 + n] = sp + b1h;
            float tv = tp + b2h;
            t_g[(size_t)bh * NN + n0 + n] = tv;
            tred[n] = tv;
        }
    }
    __syncthreads();
    // epilogue 2: coalesced Pt store
    {
        const int o   = t >> 2;
        const int nof = (t & 3) * 16;
        _Float16* dst = Pt + ((size_t)bh * SUP + o) * NN + n0 + nof;
        *(half8*)dst       = *(const half8*)&po[o * 72 + nof];
        *(half8*)(dst + 8) = *(const half8*)&po[o * 72 + nof + 8];
    }
    if (t == 0) {
        float m = -1e30f;
#pragma unroll
        for (int i = 0; i < 64; i++) m = fmaxf(m, tred[i]);
        tmax16[bh * 16 + blockIdx.x] = m;
    }
}

// ---------------------------------------------------------------------------
// k2: fused masked-softmax attention + aggregation.
// Per block: one (b,h), 64 query rows; 128-key tiles; alpha built in registers
// directly in the MFMA A-fragment layout; bitmask from Am; Z via shfl_xor.
// grid (N/64, B*H), block 256 (4 waves).
// ---------------------------------------------------------------------------
__global__ __launch_bounds__(256) void k2_attn(const unsigned char* __restrict__ Am,
                                               const _Float16* __restrict__ Pt,
                                               const float* __restrict__ s_g,
                                               const float* __restrict__ t_g,
                                               const float* __restrict__ tmax16,
                                               float* __restrict__ out) {
    __shared__ __align__(16) _Float16 vts[64 * 136];      // V^T tile [o][m], pad 8
    __shared__ __align__(16) float tl[NN];                // t[b,h,:]
    __shared__ __align__(16) unsigned char am[64 * 144];  // bitmask rows, pad 16
    __shared__ float zinv_l[64];

    const int bh = blockIdx.y;
    const int b  = bh >> 3;
    const int h  = bh & 7;
    const int n0 = blockIdx.x * 64;
    const int t    = threadIdx.x;
    const int wave = t >> 6;
    const int lane = t & 63;
    const int quad = lane >> 4;
    const int l15  = lane & 15;
    const int row4 = t >> 2;   // staging row 0..63
    const int seg  = t & 3;    // staging segment

    // stage t values (4 KB) and mask rows (8 KB)
    ((float4*)tl)[t] = ((const float4*)(t_g + (size_t)bh * NN))[t];
    {
        const uint4* asrc = (const uint4*)(Am + ((size_t)b * NN + n0 + row4) * 128 + seg * 32);
        uint4 ma = asrc[0], mb = asrc[1];
        *(uint4*)&am[row4 * 144 + seg * 32]      = ma;
        *(uint4*)&am[row4 * 144 + seg * 32 + 16] = mb;
    }
    float tmax = -1e30f;
#pragma unroll
    for (int i = 0; i < 16; i++) tmax = fmaxf(tmax, tmax16[bh * 16 + i]);

    const int myrow = wave * 16 + l15;                 // this lane's query row
    const float sv = s_g[(size_t)bh * NN + n0 + myrow];
    const float xc = sv + tmax;
    const float cv = fmaxf(xc, 0.01f * xc);            // c >= row max logit

    floatx4 acc[4];
#pragma unroll
    for (int i = 0; i < 4; i++) acc[i] = {0.f, 0.f, 0.f, 0.f};
    float zp = 0.f;

    // V^T staging pointers + prefetch of tile 0
    const _Float16* pb = Pt + ((size_t)bh * SUP + row4) * NN + seg * 32;
    half8 v0 = ((const half8*)pb)[0];
    half8 v1 = ((const half8*)pb)[1];
    half8 v2 = ((const half8*)pb)[2];
    half8 v3 = ((const half8*)pb)[3];

    for (int mt = 0; mt < 8; mt++) {
        const int m0 = mt * 128;
        {
            _Float16* d = &vts[row4 * 136 + seg * 32];
            ((half8*)d)[0] = v0; ((half8*)d)[1] = v1;
            ((half8*)d)[2] = v2; ((half8*)d)[3] = v3;
        }
        __syncthreads();
        if (mt < 7) {
            const _Float16* p = pb + m0 + 128;
            v0 = ((const half8*)p)[0];
            v1 = ((const half8*)p)[1];
            v2 = ((const half8*)p)[2];
            v3 = ((const half8*)p)[3];
        }
#pragma unroll
        for (int kk = 0; kk < 4; kk++) {
            const unsigned mbyte = am[myrow * 144 + mt * 16 + kk * 4 + quad];
            const int kbase = m0 + kk * 32 + quad * 8;
            float4 ta = *(const float4*)&tl[kbase];
            float4 tb = *(const float4*)&tl[kbase + 4];
            float tv[8] = {ta.x, ta.y, ta.z, ta.w, tb.x, tb.y, tb.z, tb.w};
            _Float16 wb[8];
#pragma unroll
            for (int j = 0; j < 8; j++) {
                float x = sv + tv[j];
                float l = fmaxf(x, 0.01f * x);         // leaky_relu
                float e = __expf(l - cv);
                float we = (mbyte & (1u << j)) ? e : 0.f;
                zp += we;
                wb[j] = (_Float16)we;
            }
            half8 af = *(half8*)wb;
#pragma unroll
            for (int ct = 0; ct < 4; ct++) {
                half8 bf = *(const half8*)&vts[(ct * 16 + l15) * 136 + kk * 32 + quad * 8];
                acc[ct] = __builtin_amdgcn_mfma_f32_16x16x32_f16(af, bf, acc[ct], 0, 0, 0);
            }
        }
        __syncthreads();
    }

    // Z reduction across quads (lanes l, l^16, l^32, l^48 share a row)
    zp += __shfl_xor(zp, 16);
    zp += __shfl_xor(zp, 32);
    if (quad == 0) zinv_l[myrow] = 1.0f / zp;
    __syncthreads();

    // epilogue: out[b][n][h*64+o] = relu(acc / Z)
#pragma unroll
    for (int r = 0; r < 4; r++) {
        const int rr = wave * 16 + quad * 4 + r;
        const float rz = zinv_l[rr];
#pragma unroll
        for (int ct = 0; ct < 4; ct++) {
            float v = acc[ct][r] * rz;
            v = v > 0.f ? v : 0.f;
            out[((size_t)b * NN + n0 + rr) * HS + h * SUP + ct * 16 + l15] = v;
        }
    }
}

// ---------------------------------------------------------------------------
extern "C" void kernel_launch(void* const* d_in, const int* in_sizes, int n_in,
                              void* d_out, int out_size, void* d_ws, size_t ws_size,
                              hipStream_t stream) {
    const float* A  = (const float*)d_in[0];
    const float* X  = (const float*)d_in[1];
    const float* W  = (const float*)d_in[2];
    const float* w1 = (const float*)d_in[3];
    const float* b1 = (const float*)d_in[4];
    const float* w2 = (const float*)d_in[5];
    const float* b2 = (const float*)d_in[6];
    float* out = (float*)d_out;

    char* ws = (char*)d_ws;
    _Float16*      Wt     = (_Float16*)(ws);                 // 524288 B
    _Float16*      Pt     = (_Float16*)(ws + 524288);        // 8388608 B
    float*         s_g    = (float*)(ws + 8912896);          // 262144 B
    float*         t_g    = (float*)(ws + 9175040);          // 262144 B
    float*         tmax16 = (float*)(ws + 9437184);          // 4096 B
    unsigned char* Am     = (unsigned char*)(ws + 9441280);  // 1048576 B

    hipLaunchKernelGGL(k0_transpose_w, dim3(IN_DIM / 64, HH), dim3(256), 0, stream, W, Wt);
    hipLaunchKernelGGL(kpack, dim3(BB * NN / 4), dim3(256), 0, stream, A, Am);
    hipLaunchKernelGGL(k1_proj, dim3(NN / 64, BB * HH), dim3(256), 0, stream,
                       X, Wt, w1, b1, w2, b2, Pt, s_g, t_g, tmax16);
    hipLaunchKernelGGL(k2_attn, dim3(NN / 64, BB * HH), dim3(256), 0, stream,
                       Am, Pt, s_g, t_g, tmax16, out);
}

// Round 3
// 136.731 us; speedup vs baseline: 1.1500x; 1.0283x over previous
//
#include <hip/hip_runtime.h>
#include <hip/hip_fp16.h>

// Problem constants (match reference)
#define BB 8
#define NN 1024
#define IN_DIM 512
#define HH 8
#define SUP 64
#define HS (HH * SUP)   // 512

typedef _Float16 half8 __attribute__((ext_vector_type(8)));
typedef float floatx4 __attribute__((ext_vector_type(4)));

// ---------------------------------------------------------------------------
// kprep: grid-split kernel.
//   blocks [0, 2048):  pack A[b][n][m] fp32 (0/1) -> bitmask Am[row][128 B]
//   blocks [2048, 2112): W[h][i][o] fp32 -> Wt[h][o][i] fp16 (transpose+cvt)
// block 256.
// ---------------------------------------------------------------------------
__global__ __launch_bounds__(256) void kprep(const float* __restrict__ A,
                                             unsigned char* __restrict__ Am,
                                             const float* __restrict__ W,
                                             _Float16* __restrict__ Wt) {
    __shared__ float tile[64][65];
    const int bid = blockIdx.x;
    const int t   = threadIdx.x;
    if (bid < 2048) {
        // ---- pack A ----
        const int gw   = bid * 4 + (t >> 6);   // row = b*N+n, 0..8191
        const int lane = t & 63;
        const float* arow = A + (size_t)gw * NN;
        unsigned long long keep = 0;
#pragma unroll
        for (int g = 0; g < 16; g++) {
            float a = arow[g * 64 + lane];
            unsigned long long bal = __ballot(a > 0.5f);
            if (lane == g) keep = bal;
        }
        if (lane < 16)
            *(unsigned long long*)(Am + (size_t)gw * 128 + lane * 8) = keep;
    } else {
        // ---- transpose W ----
        const int wb = bid - 2048;
        const int it = wb & 7;        // i-tile
        const int h  = wb >> 3;
        {
            const int i  = t >> 2;
            const int o0 = (t & 3) * 16;
            const float* src = W + ((size_t)h * IN_DIM + it * 64 + i) * SUP + o0;
#pragma unroll
            for (int j = 0; j < 4; j++) {
                float4 v = ((const float4*)src)[j];
                tile[i][o0 + j * 4 + 0] = v.x;
                tile[i][o0 + j * 4 + 1] = v.y;
                tile[i][o0 + j * 4 + 2] = v.z;
                tile[i][o0 + j * 4 + 3] = v.w;
            }
        }
        __syncthreads();
        {
            const int o  = t >> 2;
            const int i0 = (t & 3) * 16;
            _Float16 buf[16];
#pragma unroll
            for (int j = 0; j < 16; j++) buf[j] = (_Float16)tile[i0 + j][o];
            _Float16* dst = Wt + ((size_t)h * SUP + o) * IN_DIM + it * 64 + i0;
            *(half8*)dst       = *(half8*)buf;
            *(half8*)(dst + 8) = *(half8*)(buf + 8);
        }
    }
}

// ---------------------------------------------------------------------------
// k1: projection + attention logits. Per (b,h): P[1024,64] = X_b @ W_h.
// Double-buffered LDS, ONE barrier per K-slab. Stores Pt[bh][o][n] fp16,
// s = P.w1+b1, t = P.w2+b2 (from fp32 accumulators), per-tile tmax.
// grid (N/64, B*H), block 256 (4 waves).
// ---------------------------------------------------------------------------
__global__ __launch_bounds__(256) void k1_proj(const float* __restrict__ X,
                                               const _Float16* __restrict__ Wt,
                                               const float* __restrict__ w1,
                                               const float* __restrict__ b1,
                                               const float* __restrict__ w2,
                                               const float* __restrict__ b2,
                                               _Float16* __restrict__ Pt,
                                               float* __restrict__ s_g,
                                               float* __restrict__ t_g,
                                               float* __restrict__ tmax16) {
    __shared__ __align__(16) _Float16 xs[2][64 * 40];
    __shared__ __align__(16) _Float16 wsh[2][64 * 40];
    __shared__ __align__(16) _Float16 po[64 * 72];
    __shared__ float tred[64];

    const int bh = blockIdx.y;
    const int b  = bh >> 3;
    const int h  = bh & 7;
    const int n0 = blockIdx.x * 64;
    const int t    = threadIdx.x;
    const int wave = t >> 6;
    const int lane = t & 63;
    const int quad = lane >> 4;
    const int l15  = lane & 15;
    const int row  = t >> 2;
    const int koff = (t & 3) * 8;

    floatx4 acc[4];
#pragma unroll
    for (int i = 0; i < 4; i++) acc[i] = {0.f, 0.f, 0.f, 0.f};

    float w1v[4], w2v[4];
#pragma unroll
    for (int ct = 0; ct < 4; ct++) {
        w1v[ct] = w1[h * 64 + ct * 16 + l15];
        w2v[ct] = w2[h * 64 + ct * 16 + l15];
    }
    const float b1h = b1[h];
    const float b2h = b2[h];

    const float*    xbase = X + ((size_t)b * NN + n0 + row) * IN_DIM;
    const _Float16* wbase = Wt + ((size_t)h * SUP + row) * IN_DIM;

    // prefetch slab 0
    float4 xa = ((const float4*)(xbase + koff))[0];
    float4 xb = ((const float4*)(xbase + koff))[1];
    half8  wv = *(const half8*)(wbase + koff);

    for (int it = 0; it < 16; it++) {
        const int cur = it & 1;
        {
            _Float16 xh[8] = {(_Float16)xa.x, (_Float16)xa.y, (_Float16)xa.z, (_Float16)xa.w,
                              (_Float16)xb.x, (_Float16)xb.y, (_Float16)xb.z, (_Float16)xb.w};
            *(half8*)&xs[cur][row * 40 + koff]  = *(half8*)xh;
            *(half8*)&wsh[cur][row * 40 + koff] = wv;
        }
        __syncthreads();   // tile `it` visible; prior reads of buf `cur` (it-2) done
        if (it < 15) {
            const float* src = xbase + (it + 1) * 32 + koff;
            xa = ((const float4*)src)[0];
            xb = ((const float4*)src)[1];
            wv = *(const half8*)(wbase + (it + 1) * 32 + koff);
        }
        half8 af = *(const half8*)&xs[cur][(wave * 16 + l15) * 40 + quad * 8];
#pragma unroll
        for (int ct = 0; ct < 4; ct++) {
            half8 bf = *(const half8*)&wsh[cur][(ct * 16 + l15) * 40 + quad * 8];
            acc[ct] = __builtin_amdgcn_mfma_f32_16x16x32_f16(af, bf, acc[ct], 0, 0, 0);
        }
        // no second barrier: next write goes to the other buffer
    }
    __syncthreads();   // protect po reuse below against in-flight reads

    // epilogue 1: po[o][n] fp16 tile + s/t from fp32 accumulators
#pragma unroll
    for (int ct = 0; ct < 4; ct++) {
#pragma unroll
        for (int r = 0; r < 4; r++) {
            int o = ct * 16 + l15;
            int n = wave * 16 + quad * 4 + r;
            po[o * 72 + n] = (_Float16)acc[ct][r];
        }
    }
#pragma unroll
    for (int r = 0; r < 4; r++) {
        float sp = 0.f, tp = 0.f;
#pragma unroll
        for (int ct = 0; ct < 4; ct++) {
            sp += acc[ct][r] * w1v[ct];
            tp += acc[ct][r] * w2v[ct];
        }
#pragma unroll
        for (int off = 1; off < 16; off <<= 1) {
            sp += __shfl_xor(sp, off);
            tp += __shfl_xor(tp, off);
        }
        if (l15 == 0) {
            const int n = wave * 16 + quad * 4 + r;
            s_g[(size_t)bh * NN + n0 + n] = sp + b1h;
            float tv = tp + b2h;
            t_g[(size_t)bh * NN + n0 + n] = tv;
            tred[n] = tv;
        }
    }
    __syncthreads();
    // epilogue 2: coalesced Pt store
    {
        const int o   = t >> 2;
        const int nof = (t & 3) * 16;
        _Float16* dst = Pt + ((size_t)bh * SUP + o) * NN + n0 + nof;
        *(half8*)dst       = *(const half8*)&po[o * 72 + nof];
        *(half8*)(dst + 8) = *(const half8*)&po[o * 72 + nof + 8];
    }
    if (t == 0) {
        float m = -1e30f;
#pragma unroll
        for (int i = 0; i < 64; i++) m = fmaxf(m, tred[i]);
        tmax16[bh * 16 + blockIdx.x] = m;
    }
}

// ---------------------------------------------------------------------------
// k2: fused masked-softmax attention + aggregation.
// Per block: one (b,h), 128 query rows, 512 threads (8 waves).
// Double-buffered 128-key V^T tiles, ONE barrier per tile. Bitmask read
// per-wave from global (uint4/tile, L1 broadcast). Z via shfl only.
// grid (N/128, B*H), block 512.
// ---------------------------------------------------------------------------
__global__ __launch_bounds__(512) void k2_attn(const unsigned char* __restrict__ Am,
                                               const _Float16* __restrict__ Pt,
                                               const float* __restrict__ s_g,
                                               const float* __restrict__ t_g,
                                               const float* __restrict__ tmax16,
                                               float* __restrict__ out) {
    __shared__ __align__(16) _Float16 vts[2][64 * 136];  // V^T tile [o][m], pad 8
    __shared__ __align__(16) float tl[NN];               // t[b,h,:]

    const int bh = blockIdx.y;
    const int b  = bh >> 3;
    const int h  = bh & 7;
    const int n0 = blockIdx.x * 128;
    const int t    = threadIdx.x;
    const int wave = t >> 6;
    const int lane = t & 63;
    const int quad = lane >> 4;
    const int l15  = lane & 15;
    const int row4 = t >> 3;   // staging o-row 0..63
    const int seg  = t & 7;    // staging segment (16 keys each)

    // stage t values (4 KB)
    ((float2*)tl)[t] = ((const float2*)(t_g + (size_t)bh * NN))[t];

    float tmax = -1e30f;
#pragma unroll
    for (int i = 0; i < 16; i++) tmax = fmaxf(tmax, tmax16[bh * 16 + i]);

    const int myrow = wave * 16 + l15;                 // this lane's query row (0..127)
    const float sv = s_g[(size_t)bh * NN + n0 + myrow];
    const float xc = sv + tmax;
    const float cv = fmaxf(xc, 0.01f * xc);            // c >= row max logit

    floatx4 acc[4];
#pragma unroll
    for (int i = 0; i < 4; i++) acc[i] = {0.f, 0.f, 0.f, 0.f};
    float zp = 0.f;

    // V^T staging pointer + prefetch tile 0
    const _Float16* pb = Pt + ((size_t)bh * SUP + row4) * NN + seg * 16;
    half8 v0 = ((const half8*)pb)[0];
    half8 v1 = ((const half8*)pb)[1];
    // mask row pointer + prefetch tile 0 (16 B per 128-key tile)
    const uint4* mrow = (const uint4*)(Am + ((size_t)b * NN + n0 + myrow) * 128);
    uint4 mcur = mrow[0];

    for (int mt = 0; mt < 8; mt++) {
        const int cur = mt & 1;
        {
            _Float16* d = &vts[cur][row4 * 136 + seg * 16];
            ((half8*)d)[0] = v0;
            ((half8*)d)[1] = v1;
        }
        __syncthreads();   // single barrier: tile mt visible, buf `cur` reads (mt-2) drained
        uint4 mnext;
        if (mt < 7) {
            const _Float16* p = pb + (mt + 1) * 128;
            v0 = ((const half8*)p)[0];
            v1 = ((const half8*)p)[1];
            mnext = mrow[mt + 1];
        }
        const unsigned mw[4] = {mcur.x, mcur.y, mcur.z, mcur.w};
        const int m0 = mt * 128;
#pragma unroll
        for (int kk = 0; kk < 4; kk++) {
            const unsigned mbyte = (mw[kk] >> (quad * 8)) & 0xffu;
            const int kbase = m0 + kk * 32 + quad * 8;
            float4 ta = *(const float4*)&tl[kbase];
            float4 tb = *(const float4*)&tl[kbase + 4];
            float tv[8] = {ta.x, ta.y, ta.z, ta.w, tb.x, tb.y, tb.z, tb.w};
            _Float16 wb[8];
#pragma unroll
            for (int j = 0; j < 8; j++) {
                float x = sv + tv[j];
                float l = fmaxf(x, 0.01f * x);         // leaky_relu
                float e = __expf(l - cv);
                float we = (mbyte & (1u << j)) ? e : 0.f;
                zp += we;
                wb[j] = (_Float16)we;
            }
            half8 af = *(half8*)wb;
#pragma unroll
            for (int ct = 0; ct < 4; ct++) {
                half8 bf = *(const half8*)&vts[cur][(ct * 16 + l15) * 136 + kk * 32 + quad * 8];
                acc[ct] = __builtin_amdgcn_mfma_f32_16x16x32_f16(af, bf, acc[ct], 0, 0, 0);
            }
        }
        if (mt < 7) mcur = mnext;
    }

    // Z reduction across quads (lanes sharing a row), then distribute 1/Z by shfl
    zp += __shfl_xor(zp, 16);
    zp += __shfl_xor(zp, 32);
    const float rzown = 1.0f / zp;   // valid for row `myrow` on every lane

    // epilogue: out[b][n][h*64+o] = relu(acc / Z)
#pragma unroll
    for (int r = 0; r < 4; r++) {
        const int rr = wave * 16 + quad * 4 + r;
        // 1/Z for row rr lives in lanes with l15 == quad*4+r; take the one in our quad
        const float rz = __shfl(rzown, quad * 20 + r);
#pragma unroll
        for (int ct = 0; ct < 4; ct++) {
            float v = acc[ct][r] * rz;
            v = v > 0.f ? v : 0.f;
            out[((size_t)b * NN + n0 + rr) * HS + h * SUP + ct * 16 + l15] = v;
        }
    }
}

// ---------------------------------------------------------------------------
extern "C" void kernel_launch(void* const* d_in, const int* in_sizes, int n_in,
                              void* d_out, int out_size, void* d_ws, size_t ws_size,
                              hipStream_t stream) {
    const float* A  = (const float*)d_in[0];
    const float* X  = (const float*)d_in[1];
    const float* W  = (const float*)d_in[2];
    const float* w1 = (const float*)d_in[3];
    const float* b1 = (const float*)d_in[4];
    const float* w2 = (const float*)d_in[5];
    const float* b2 = (const float*)d_in[6];
    float* out = (float*)d_out;

    char* ws = (char*)d_ws;
    _Float16*      Wt     = (_Float16*)(ws);                 // 524288 B
    _Float16*      Pt     = (_Float16*)(ws + 524288);        // 8388608 B
    float*         s_g    = (float*)(ws + 8912896);          // 262144 B
    float*         t_g    = (float*)(ws + 9175040);          // 262144 B
    float*         tmax16 = (float*)(ws + 9437184);          // 4096 B
    unsigned char* Am     = (unsigned char*)(ws + 9441280);  // 1048576 B

    hipLaunchKernelGGL(kprep, dim3(2048 + 64), dim3(256), 0, stream, A, Am, W, Wt);
    hipLaunchKernelGGL(k1_proj, dim3(NN / 64, BB * HH), dim3(256), 0, stream,
                       X, Wt, w1, b1, w2, b2, Pt, s_g, t_g, tmax16);
    hipLaunchKernelGGL(k2_attn, dim3(NN / 128, BB * HH), dim3(512), 0, stream,
                       Am, Pt, s_g, t_g, tmax16, out);
}